// Round 7
// baseline (606.551 us; speedup 1.0000x reference)
//
#include <hip/hip_runtime.h>
#include <hip/hip_bf16.h>
#include <stdint.h>

// Window attention, Swin-style. B=4096 windows, N=49, C=256, NH=8, D=32.
// FULLY FUSED v6: one block per window (512 thr, 8 waves), wave w owns head w.
// vs v5: (1) k_prep rewritten as coalesced LDS-tiled transpose (~10us vs ~210us),
// (2) rpb gather replaced by precomputed RB[8][64][64] bias table (float4 loads,
// kills 2.2e7 LDS bank conflicts + per-element /7 index math),
// (3) native bf16 converts (v_cvt_pk) + depth-2 weight prefetch in K-loops.

typedef __attribute__((ext_vector_type(8))) short bf16x8;
typedef __attribute__((ext_vector_type(4))) float f32x4;

__device__ __forceinline__ unsigned short f2bfu(float f) {
    __hip_bfloat16 h = __float2bfloat16(f);           // RNE; pairs fuse to v_cvt_pk
    return *reinterpret_cast<unsigned short*>(&h);
}
__device__ __forceinline__ unsigned pk2(float a, float b) {
    return (unsigned)f2bfu(a) | ((unsigned)f2bfu(b) << 16);
}

// ---- K0 v2: blocks 0..15: coalesced transpose of weights into Wcat (bf16),
//      rows 0..767 = qkv feats (src qkv_w [256k][768n]),
//      rows 768..1023 = proj feats (src proj_w [256k][256n]).
//      blocks 16..143: RB[8h][64n][64m] fp32 bias table. ----
__global__ __launch_bounds__(256) void k_prep(const float* __restrict__ qkv_w,
        const float* __restrict__ proj_w, const float* __restrict__ rpb,
        short* __restrict__ Wcat, float* __restrict__ RB) {
    int blk = blockIdx.x;
    int t = threadIdx.x;
    if (blk < 16) {
        __shared__ float ft[64 * 65];                 // 64 k-rows x 64 n-cols, pad 65
        int n0 = blk * 64;
        const float* src;
        int stride, c0;
        if (blk < 12) { src = qkv_w;  stride = 768; c0 = n0; }
        else          { src = proj_w; stride = 256; c0 = n0 - 768; }
        for (int k0 = 0; k0 < 256; k0 += 64) {
            __syncthreads();                          // protect prev-iter LDS reads
            #pragma unroll
            for (int i = 0; i < 4; i++) {             // load 64x64 fp32, coalesced
                int idx = i * 256 + t;
                int kk = idx >> 4, c4 = (idx & 15) * 4;
                float4 v = *(const float4*)(src + (size_t)(k0 + kk) * stride + c0 + c4);
                float* d = &ft[kk * 65 + c4];
                d[0] = v.x; d[1] = v.y; d[2] = v.z; d[3] = v.w;
            }
            __syncthreads();
            #pragma unroll
            for (int j = 0; j < 2; j++) {             // write 64n x 64k bf16, coalesced
                int idx = j * 256 + t;
                int nn = idx >> 3, c8 = (idx & 7) * 8;
                unsigned u0 = pk2(ft[(c8 + 0) * 65 + nn], ft[(c8 + 1) * 65 + nn]);
                unsigned u1 = pk2(ft[(c8 + 2) * 65 + nn], ft[(c8 + 3) * 65 + nn]);
                unsigned u2 = pk2(ft[(c8 + 4) * 65 + nn], ft[(c8 + 5) * 65 + nn]);
                unsigned u3 = pk2(ft[(c8 + 6) * 65 + nn], ft[(c8 + 7) * 65 + nn]);
                *(uint4*)&Wcat[(size_t)(n0 + nn) * 256 + k0 + c8] =
                    make_uint4(u0, u1, u2, u3);
            }
        }
    } else {
        int flat = (blk - 16) * 256 + t;              // 32768 = 8h * 64n * 64m
        int h = flat >> 12, n = (flat >> 6) & 63, m = flat & 63;
        float v = 0.f;
        if (n < 49 && m < 49) {
            int ni = n / 7, nj = n - 7 * ni;
            int mi = m / 7, mj = m - 7 * mi;
            int idx = (ni - mi + 6) * 13 + (nj - mj + 6);
            v = rpb[idx * 8 + h];
        }
        RB[flat] = v;
    }
}

// LDS map (shorts). Total 34816 shorts = 69632 B -> 2 blocks/CU.
//   XS @ 0      [64tok][256k] (chunk-swz) 32 KB   } aliased: XS dead after phase-1
//   AO @ 0      [8h][64tok][32d] (chunk-swz)      } passes (barrier #2 separates)
//   SW @ 16384  per-wave 2304-short scratch, time-shared:
//               Q[64][32] -> q-frags -> K[64][32] -> k-frags
//               -> V^T[32][72] -> v-frags -> P[16][72]
#define XS_OFF 0
#define AO_OFF 0
#define SW_OFF 16384

// One QKV sub-GEMM pass (part P: 0=Q,1=K,2=V): 32 feats x 64 tok x K=256.
// Depth-2 weight prefetch: next-iter L2 loads issue before current MFMAs.
#define QKV_PASS(P, ACC)                                                          \
    {                                                                             \
        const short* wb = Wq + (size_t)((P) * 256 + w * 32 + l15) * 256 + g * 8;  \
        bf16x8 c0 = *(const bf16x8*)(wb);                                         \
        bf16x8 c1 = *(const bf16x8*)(wb + 4096);                                  \
        _Pragma("unroll")                                                         \
        for (int ks = 0; ks < 8; ks++) {                                          \
            bf16x8 p0, p1;                                                        \
            if (ks < 7) {                                                         \
                p0 = *(const bf16x8*)(wb + (ks + 1) * 32);                        \
                p1 = *(const bf16x8*)(wb + 4096 + (ks + 1) * 32);                 \
            }                                                                     \
            int xsl = (((ks << 2) + g) ^ (l15 & 7)) << 3;                         \
            _Pragma("unroll")                                                     \
            for (int j = 0; j < 4; j++) {                                         \
                bf16x8 bfj = *(const bf16x8*)&smem[XS_OFF + (j * 16 + l15) * 256 + xsl]; \
                ACC[0][j] = __builtin_amdgcn_mfma_f32_16x16x32_bf16(c0, bfj, ACC[0][j], 0, 0, 0); \
                ACC[1][j] = __builtin_amdgcn_mfma_f32_16x16x32_bf16(c1, bfj, ACC[1][j], 0, 0, 0); \
            }                                                                     \
            if (ks < 7) { c0 = p0; c1 = p1; }                                     \
        }                                                                         \
    }

__global__ __launch_bounds__(512, 4) void k_fused(
        const float* __restrict__ x, const short* __restrict__ Wq,
        const short* __restrict__ Wp, const float* __restrict__ qkv_b,
        const float* __restrict__ RB, const float* __restrict__ proj_b,
        float* __restrict__ out) {
    __shared__ __align__(16) short smem[34816];

    const int b = blockIdx.x;
    const int t = threadIdx.x;
    const int w = t >> 6, lane = t & 63;
    const int l15 = lane & 15, g = lane >> 4;
    const int cs8 = (l15 >> 1) & 3;               // chunk-swz field for 32-short rows
    const int swz = (g ^ cs8) << 3;               // swizzled frag chunk offset

    f32x4 zero = {0.f, 0.f, 0.f, 0.f};

    // ---- phase 0: x fp32 -> bf16 -> XS (chunk-swz), zero-pad rows 49..63 ----
    #pragma unroll
    for (int i = 0; i < 4; i++) {
        int cid = t + i * 512;                    // 2048 granules = 64 tok x 32 chunks
        int tok = cid >> 5, c = cid & 31;
        uint4 w4 = make_uint4(0u, 0u, 0u, 0u);
        if (tok < 49) {
            const float4* s = (const float4*)(x + ((size_t)b * 49 + tok) * 256 + c * 8);
            float4 f0 = s[0], f1 = s[1];
            w4 = make_uint4(pk2(f0.x, f0.y), pk2(f0.z, f0.w),
                            pk2(f1.x, f1.y), pk2(f1.z, f1.w));
        }
        *(uint4*)&smem[XS_OFF + tok * 256 + ((c ^ (tok & 7)) << 3)] = w4;
    }
    __syncthreads();   // barrier #1: XS visible

    // ---- phase 1: three low-pressure passes. Wave w = head w.
    //      Each pass: acc[2][4] (32 regs) -> stage into SW -> read frags. ----
    short* SW = &smem[SW_OFF + w * 2304];         // per-wave scratch
    const int d0a = g * 4;                        // it=0 feature base
    const int d0b = 16 + g * 4;                   // it=1 feature base
    const int sda = (((d0a >> 3) ^ cs8) << 3) + (d0a & 7);
    const int sdb = (((d0b >> 3) ^ cs8) << 3) + (d0b & 7);

    bf16x8 qb4[4], ka[4], va[2][2];

    {   // --- Q pass ---
        f32x4 aq[2][4];
        #pragma unroll
        for (int i = 0; i < 2; i++)
            #pragma unroll
            for (int j = 0; j < 4; j++) aq[i][j] = zero;
        QKV_PASS(0, aq)
        #pragma unroll
        for (int it = 0; it < 2; it++) {
            float4 bv = *(const float4*)&qkv_b[w * 32 + it * 16 + d0a];
            int sd = it ? sdb : sda;
            #pragma unroll
            for (int j = 0; j < 4; j++) {
                f32x4 a = aq[it][j];
                unsigned* dst = (unsigned*)&SW[(j * 16 + l15) * 32 + sd];
                dst[0] = pk2(a[0] + bv.x, a[1] + bv.y);
                dst[1] = pk2(a[2] + bv.z, a[3] + bv.w);
            }
        }
        #pragma unroll
        for (int nt = 0; nt < 4; nt++)
            qb4[nt] = *(const bf16x8*)&SW[(nt * 16 + l15) * 32 + swz];
    }
    {   // --- K pass (overwrites SW) ---
        f32x4 ak[2][4];
        #pragma unroll
        for (int i = 0; i < 2; i++)
            #pragma unroll
            for (int j = 0; j < 4; j++) ak[i][j] = zero;
        QKV_PASS(1, ak)
        #pragma unroll
        for (int it = 0; it < 2; it++) {
            float4 bv = *(const float4*)&qkv_b[256 + w * 32 + it * 16 + d0a];
            int sd = it ? sdb : sda;
            #pragma unroll
            for (int j = 0; j < 4; j++) {
                f32x4 a = ak[it][j];
                unsigned* dst = (unsigned*)&SW[(j * 16 + l15) * 32 + sd];
                dst[0] = pk2(a[0] + bv.x, a[1] + bv.y);
                dst[1] = pk2(a[2] + bv.z, a[3] + bv.w);
            }
        }
        #pragma unroll
        for (int mt = 0; mt < 4; mt++)
            ka[mt] = *(const bf16x8*)&SW[(mt * 16 + l15) * 32 + swz];
    }
    {   // --- V pass (overwrites SW with V^T [32d][72tok]) ---
        f32x4 av[2][4];
        #pragma unroll
        for (int i = 0; i < 2; i++)
            #pragma unroll
            for (int j = 0; j < 4; j++) av[i][j] = zero;
        QKV_PASS(2, av)
        #pragma unroll
        for (int it = 0; it < 2; it++) {
            float4 bv = *(const float4*)&qkv_b[512 + w * 32 + it * 16 + d0a];
            int d0 = it * 16 + d0a;
            #pragma unroll
            for (int j = 0; j < 4; j++) {
                int tok = j * 16 + l15;
                f32x4 a = av[it][j];
                SW[(d0 + 0) * 72 + tok] = (short)f2bfu(a[0] + bv.x);
                SW[(d0 + 1) * 72 + tok] = (short)f2bfu(a[1] + bv.y);
                SW[(d0 + 2) * 72 + tok] = (short)f2bfu(a[2] + bv.z);
                SW[(d0 + 3) * 72 + tok] = (short)f2bfu(a[3] + bv.w);
            }
        }
        #pragma unroll
        for (int dt = 0; dt < 2; dt++)
            #pragma unroll
            for (int kk = 0; kk < 2; kk++)
                va[dt][kk] = *(const bf16x8*)&SW[(dt * 16 + l15) * 72 + kk * 32 + g * 8];
    }
    __syncthreads();   // barrier #2: all XS reads done (AO aliases XS below)

    // ---- phase 2: attention, fully wave-local (head h = w), no barriers ----
    {
        const int h = w;
        short* Plw = SW;                          // P scratch reuses SW[0..1152)
        short* AOw = &smem[AO_OFF + h * 2048];    // AO [h][tok][32] chunk-swz
        const float scale = 0.17677669529663687f; // 1/sqrt(32)

        #pragma unroll
        for (int nt = 0; nt < 4; nt++) {
            int n = nt * 16 + l15;
            // bias fragment loads (L2-resident RB), issued before the MFMAs
            const float* RBp = RB + (((h << 6) + n) << 6) + (g << 2);
            f32x4 bb[4];
            #pragma unroll
            for (int mt = 0; mt < 4; mt++) bb[mt] = *(const f32x4*)(RBp + mt * 16);
            f32x4 s4[4];
            #pragma unroll
            for (int mt = 0; mt < 4; mt++)
                s4[mt] = __builtin_amdgcn_mfma_f32_16x16x32_bf16(ka[mt], qb4[nt], zero, 0, 0, 0);
            #pragma unroll
            for (int mt = 0; mt < 4; mt++)
                #pragma unroll
                for (int r = 0; r < 4; r++) {
                    int m = mt * 16 + g * 4 + r;
                    float val = s4[mt][r] * scale + bb[mt][r];
                    s4[mt][r] = (m < 49) ? val : -1e30f;
                }
            float tmax = -1e30f;
            #pragma unroll
            for (int mt = 0; mt < 4; mt++)
                #pragma unroll
                for (int r = 0; r < 4; r++) tmax = fmaxf(tmax, s4[mt][r]);
            tmax = fmaxf(tmax, __shfl_xor(tmax, 16));
            tmax = fmaxf(tmax, __shfl_xor(tmax, 32));
            float rsum = 0.f;
            #pragma unroll
            for (int mt = 0; mt < 4; mt++)
                #pragma unroll
                for (int r = 0; r < 4; r++) {
                    float e = __expf(s4[mt][r] - tmax);
                    s4[mt][r] = e;
                    rsum += e;
                }
            rsum += __shfl_xor(rsum, 16);
            rsum += __shfl_xor(rsum, 32);

            // P (unnormalized) -> Plw[n'][m]; wave-local, in-order LDS => no barrier
            #pragma unroll
            for (int mt = 0; mt < 4; mt++) {
                unsigned* dst = (unsigned*)&Plw[l15 * 72 + mt * 16 + g * 4];
                dst[0] = pk2(s4[mt][0], s4[mt][1]);
                dst[1] = pk2(s4[mt][2], s4[mt][3]);
            }
            bf16x8 pb0 = *(const bf16x8*)&Plw[l15 * 72 + g * 8];
            bf16x8 pb1 = *(const bf16x8*)&Plw[l15 * 72 + 32 + g * 8];
            f32x4 o0 = __builtin_amdgcn_mfma_f32_16x16x32_bf16(va[0][0], pb0, zero, 0, 0, 0);
            o0 = __builtin_amdgcn_mfma_f32_16x16x32_bf16(va[0][1], pb1, o0, 0, 0, 0);
            f32x4 o1 = __builtin_amdgcn_mfma_f32_16x16x32_bf16(va[1][0], pb0, zero, 0, 0, 0);
            o1 = __builtin_amdgcn_mfma_f32_16x16x32_bf16(va[1][1], pb1, o1, 0, 0, 0);
            float inv = 1.f / rsum;
            {
                unsigned* dst = (unsigned*)&AOw[n * 32 + sda];
                dst[0] = pk2(o0[0] * inv, o0[1] * inv);
                dst[1] = pk2(o0[2] * inv, o0[3] * inv);
            }
            {
                unsigned* dst = (unsigned*)&AOw[n * 32 + sdb];
                dst[0] = pk2(o1[0] * inv, o1[1] * inv);
                dst[1] = pk2(o1[2] * inv, o1[3] * inv);
            }
        }
    }
    __syncthreads();   // barrier #3: all heads' AO visible for proj

    // ---- phase 3: proj GEMM. Wave w computes out-feats [w*32, w*32+32).
    //      A-frags (Wp) from L2, depth-2 prefetch; B-frags from AO. ----
    {
        f32x4 acc2[2][4];
        #pragma unroll
        for (int i = 0; i < 2; i++)
            #pragma unroll
            for (int j = 0; j < 4; j++) acc2[i][j] = zero;

        const short* pbase = Wp + (size_t)(w * 32 + l15) * 256 + g * 8;
        bf16x8 c0 = *(const bf16x8*)(pbase);
        bf16x8 c1 = *(const bf16x8*)(pbase + 4096);
        #pragma unroll
        for (int ks = 0; ks < 8; ks++) {
            bf16x8 p0, p1;
            if (ks < 7) {
                p0 = *(const bf16x8*)(pbase + (ks + 1) * 32);
                p1 = *(const bf16x8*)(pbase + 4096 + (ks + 1) * 32);
            }
            #pragma unroll
            for (int j = 0; j < 4; j++) {
                bf16x8 bf2 = *(const bf16x8*)&smem[AO_OFF + ks * 2048 + (j * 16 + l15) * 32 + swz];
                acc2[0][j] = __builtin_amdgcn_mfma_f32_16x16x32_bf16(c0, bf2, acc2[0][j], 0, 0, 0);
                acc2[1][j] = __builtin_amdgcn_mfma_f32_16x16x32_bf16(c1, bf2, acc2[1][j], 0, 0, 0);
            }
            if (ks < 7) { c0 = p0; c1 = p1; }
        }
        #pragma unroll
        for (int it = 0; it < 2; it++) {
            int fo = w * 32 + it * 16 + g * 4;
            float4 bv = *(const float4*)&proj_b[fo];
            #pragma unroll
            for (int j = 0; j < 4; j++) {
                int tok = j * 16 + l15;
                if (tok < 49) {
                    f32x4 a = acc2[it][j];
                    float4 val = make_float4(a[0] + bv.x, a[1] + bv.y,
                                             a[2] + bv.z, a[3] + bv.w);
                    *(float4*)&out[((size_t)b * 49 + tok) * 256 + fo] = val;
                }
            }
        }
    }
}

extern "C" void kernel_launch(void* const* d_in, const int* in_sizes, int n_in,
                              void* d_out, int out_size, void* d_ws, size_t ws_size,
                              hipStream_t stream) {
    const float* x      = (const float*)d_in[0];
    const float* qkv_w  = (const float*)d_in[1];
    const float* qkv_b  = (const float*)d_in[2];
    const float* rpb    = (const float*)d_in[3];
    const float* proj_w = (const float*)d_in[4];
    const float* proj_b = (const float*)d_in[5];
    float* out = (float*)d_out;

    // ws: Wcat[1024*256 bf16] (rows 0..767 qkv^T, 768..1023 proj^T) | RB[8*64*64 f32]
    short* Wcat = (short*)d_ws;
    float* RB   = (float*)(Wcat + 1024 * 256);
    if (ws_size < 655360ull) return;   // 512 KB + 128 KB

    k_prep<<<144, 256, 0, stream>>>(qkv_w, proj_w, rpb, Wcat, RB);
    k_fused<<<4096, 512, 0, stream>>>(x, Wcat, Wcat + 768 * 256, qkv_b, RB, proj_b, out);
}